// Round 6
// baseline (4259.023 us; speedup 1.0000x reference)
//
#include <hip/hip_runtime.h>
#include <hip/hip_bf16.h>
#include <float.h>
#include <math.h>

#define K_DIM 768
#define V_DIM 50257
#define M_TOT 4096
#define BM 128
#define BN 128
#define BK 16
#define NSPLIT 16
#define NTILES ((V_DIM + BN - 1) / BN)   // 393
#define EMB_N 3145728                    // 2*2048*768
#define TAB_N 38597376                   // 50257*768

// ---------------- JAX threefry2x32 (key = (0, 42)), 20 rounds ----------------
// Core verified vs Random123/JAX KAT: key=(0,0), msg=(0,0) -> {6b200159, 99ba4efe}
__device__ __forceinline__ unsigned rotl32(unsigned v, int d) {
  return (v << d) | (v >> (32 - d));
}

__device__ __forceinline__ void threefry2x32_042(unsigned& x0, unsigned& x1) {
  const unsigned ks0 = 0u, ks1 = 42u;
  const unsigned ks2 = ks0 ^ ks1 ^ 0x1BD11BDAu;
  x0 += ks0; x1 += ks1;
#define TF_R(r) { x0 += x1; x1 = rotl32(x1, (r)); x1 ^= x0; }
  TF_R(13) TF_R(15) TF_R(26) TF_R(6)
  x0 += ks1; x1 += ks2 + 1u;
  TF_R(17) TF_R(29) TF_R(16) TF_R(24)
  x0 += ks2; x1 += ks0 + 2u;
  TF_R(13) TF_R(15) TF_R(26) TF_R(6)
  x0 += ks0; x1 += ks1 + 3u;
  TF_R(17) TF_R(29) TF_R(16) TF_R(24)
  x0 += ks1; x1 += ks2 + 4u;
  TF_R(13) TF_R(15) TF_R(26) TF_R(6)
  x0 += ks2; x1 += ks0 + 5u;
#undef TF_R
}

// bits -> uniform(-1+2^-24, 1) -> laplace -> /5  (exact JAX op sequence)
__device__ __forceinline__ float bits_to_noise(unsigned bits) {
  unsigned fb = (bits >> 9) | 0x3F800000u;
  float f = __uint_as_float(fb) - 1.0f;              // [0, 1), exact
  const float minv = -0.99999994039535522461f;       // f32(-1 + 2^-24)
  float u = __fadd_rn(__fmul_rn(f, 2.0f), minv);     // f*2 exact; one rounding
  u = fmaxf(minv, u);
  float s = (u > 0.0f) ? 1.0f : ((u < 0.0f) ? -1.0f : 0.0f);
  float l = s * log1pf(-fabsf(u));                   // sign(u)*log1p(-|u|)
  return __fdiv_rn(l, 5.0f);                         // / EPSILON
}

// order-preserving (value, index) packing for u64 atomicMax:
// high 32 = monotone key of float, low 32 = 0xFFFFFFFF - idx
// => max picks larger sim; on exact tie, smaller idx (matches jnp.argmax).
__device__ __forceinline__ unsigned long long pack_maxidx(float v, int idx) {
  unsigned b = __float_as_uint(v);
  unsigned key = (b & 0x80000000u) ? ~b : (b | 0x80000000u);
  return ((unsigned long long)key << 32) |
         (unsigned long long)(0xFFFFFFFFu - (unsigned)idx);
}

// ---------------- kernel 1: noisy = inputs + laplace noise ------------------
// JAX threefry_partitionable stream, bit_width=32: element i ->
// (b1, b2) = threefry(key, (hi=0, lo=i)); bits = b1 ^ b2.
__global__ void noise_add_kernel(const float* __restrict__ in,
                                 float* __restrict__ noisy,
                                 unsigned long long* __restrict__ merged) {
  const unsigned i = blockIdx.x * blockDim.x + threadIdx.x;
  if (i >= EMB_N) return;
  if (i < M_TOT) merged[i] = 0ull;     // re-init every call (poison-safe)
  unsigned x0 = 0u, x1 = i;            // counter u64 = i: msg (hi, lo)
  threefry2x32_042(x0, x1);
  noisy[i] = in[i] + bits_to_noise(x0 ^ x1);
}

// ---------------- kernel 2: fused fp32 GEMM + row argmax (atomic merge) -----
__global__ __launch_bounds__(256) void gemm_argmax_kernel(
    const float* __restrict__ noisy, const float* __restrict__ table,
    unsigned long long* __restrict__ merged) {
  __shared__ float As[BK][BM + 4];
  __shared__ float Bs[BK][BN + 4];
  __shared__ float redm[BM][16];
  __shared__ int   redi[BM][16];

  const int tid = threadIdx.x;
  const int lane = tid & 63;
  const int w = tid >> 6;
  const int tx = lane & 7, ty = lane >> 3;       // 8x8 lanes within wave
  const int col0 = (w & 1) * 64 + tx * 8;
  const int row0 = (w >> 1) * 64 + ty * 8;
  const int bm = blockIdx.x;        // M tile: 0..31
  const int split = blockIdx.y;     // N split: 0..NSPLIT-1
  const float* Abase = noisy + (size_t)bm * BM * K_DIM;

  float rmax[8];
  int   ridx[8];
#pragma unroll
  for (int r = 0; r < 8; ++r) { rmax[r] = -INFINITY; ridx[r] = 0x7FFFFFFF; }

  for (int t = split; t < NTILES; t += NSPLIT) {
    const int nbase = t * BN;
    float acc[8][8];
#pragma unroll
    for (int r = 0; r < 8; ++r)
#pragma unroll
      for (int c = 0; c < 8; ++c) acc[r][c] = 0.0f;

    for (int k0 = 0; k0 < K_DIM; k0 += BK) {
      __syncthreads();   // previous LDS tile fully consumed
#pragma unroll
      for (int l = 0; l < 2; ++l) {
        const int e = tid + l * 256;             // 512 float4 per operand
        const int ml = e >> 2, kk = (e & 3) << 2;
        float4 av = *(const float4*)(Abase + (size_t)ml * K_DIM + k0 + kk);
        As[kk + 0][ml] = av.x; As[kk + 1][ml] = av.y;
        As[kk + 2][ml] = av.z; As[kk + 3][ml] = av.w;
        const int n = nbase + ml;
        float4 bv = make_float4(0.f, 0.f, 0.f, 0.f);
        if (n < V_DIM)
          bv = *(const float4*)(table + (size_t)n * K_DIM + k0 + kk);
        Bs[kk + 0][ml] = bv.x; Bs[kk + 1][ml] = bv.y;
        Bs[kk + 2][ml] = bv.z; Bs[kk + 3][ml] = bv.w;
      }
      __syncthreads();
#pragma unroll
      for (int k = 0; k < BK; ++k) {
        float4 a0 = *(const float4*)&As[k][row0];
        float4 a1 = *(const float4*)&As[k][row0 + 4];
        float4 b0 = *(const float4*)&Bs[k][col0];
        float4 b1 = *(const float4*)&Bs[k][col0 + 4];
        float a[8] = {a0.x, a0.y, a0.z, a0.w, a1.x, a1.y, a1.z, a1.w};
        float b[8] = {b0.x, b0.y, b0.z, b0.w, b1.x, b1.y, b1.z, b1.w};
#pragma unroll
        for (int r = 0; r < 8; ++r)
#pragma unroll
          for (int c = 0; c < 8; ++c)
            acc[r][c] = fmaf(a[r], b[c], acc[r][c]);
      }
    }
    // fold tile into running per-row argmax (strict > keeps lowest index;
    // n ascends across t within a thread -> matches jnp.argmax ties)
#pragma unroll
    for (int r = 0; r < 8; ++r) {
#pragma unroll
      for (int c = 0; c < 8; ++c) {
        const int n = nbase + col0 + c;
        if (n < V_DIM && acc[r][c] > rmax[r]) { rmax[r] = acc[r][c]; ridx[r] = n; }
      }
    }
  }

  __syncthreads();
#pragma unroll
  for (int r = 0; r < 8; ++r) {
    redm[row0 + r][(w & 1) * 8 + tx] = rmax[r];
    redi[row0 + r][(w & 1) * 8 + tx] = ridx[r];
  }
  __syncthreads();
  if (tid < BM) {
    float best = -INFINITY; int bi = 0x7FFFFFFF;
#pragma unroll
    for (int j = 0; j < 16; ++j) {
      float v = redm[tid][j]; int id = redi[tid][j];
      if (v > best || (v == best && id < bi)) { best = v; bi = id; }
    }
    atomicMax(&merged[bm * BM + tid], pack_maxidx(best, bi));
  }
}

// ---------------- kernel 3: unpack index + gather table row -----------------
__global__ void gather_kernel(const unsigned long long* __restrict__ merged,
                              const float* __restrict__ table,
                              float* __restrict__ out) {
  const int row = blockIdx.x;
  const int tid = threadIdx.x;
  const unsigned bi =
      0xFFFFFFFFu - (unsigned)(merged[row] & 0xFFFFFFFFull);
  if (tid < 192) {   // 768 floats = 192 float4, bit-exact row copy
    float4 val = *(const float4*)(table + (size_t)bi * K_DIM + tid * 4);
    *(float4*)(out + (size_t)row * K_DIM + tid * 4) = val;
  }
}

// ---------------- launch ----------------
extern "C" void kernel_launch(void* const* d_in, const int* in_sizes, int n_in,
                              void* d_out, int out_size, void* d_ws, size_t ws_size,
                              hipStream_t stream) {
  // Select inputs BY SIZE, not position (robust to ordering):
  //   inputs_embeds: 3145728 elems; embed_table: 38597376 elems
  const float* inputs = (const float*)d_in[0];
  const float* table  = (const float*)d_in[1];
  if (n_in >= 2) {
    if (in_sizes[0] == TAB_N || in_sizes[1] == EMB_N) {
      table  = (const float*)d_in[0];
      inputs = (const float*)d_in[1];
    }
  }
  float* out = (float*)d_out;

  // noisy embeddings live in d_out (overwritten by the gather at the end);
  // workspace use is just 4096 packed u64 (32 KB).
  float* noisy = out;
  unsigned long long* merged = (unsigned long long*)d_ws;

  noise_add_kernel<<<EMB_N / 256, 256, 0, stream>>>(inputs, noisy, merged);

  dim3 g2(M_TOT / BM, NSPLIT);
  gemm_argmax_kernel<<<g2, 256, 0, stream>>>(noisy, table, merged);

  gather_kernel<<<M_TOT, 256, 0, stream>>>(merged, table, out);
}

// Round 7
// 1210.394 us; speedup vs baseline: 3.5187x; 3.5187x over previous
//
#include <hip/hip_runtime.h>
#include <hip/hip_bf16.h>
#include <float.h>
#include <math.h>

#define K_DIM 768
#define V_DIM 50257
#define PADV  50304              // 393*128 padded vocab
#define M_TOT 4096
#define EMB_N 3145728            // 2*2048*768
#define TAB_N 38597376           // 50257*768
#define NT128 393                // N tiles of 128
#define GSPLIT 32                // N splits for MFMA kernel
#define NCAND 64                 // GSPLIT * top2
#define NSPLIT 16                // fallback fp32 kernel splits
#define NTILES ((V_DIM + 127) / 128)

typedef __attribute__((ext_vector_type(8))) short short8;
typedef __attribute__((ext_vector_type(4))) float f32x4;
typedef unsigned long long u64;

// ---------------- JAX threefry2x32 (key = (0, 42)), 20 rounds ----------------
__device__ __forceinline__ unsigned rotl32(unsigned v, int d) {
  return (v << d) | (v >> (32 - d));
}
__device__ __forceinline__ void threefry2x32_042(unsigned& x0, unsigned& x1) {
  const unsigned ks0 = 0u, ks1 = 42u;
  const unsigned ks2 = ks0 ^ ks1 ^ 0x1BD11BDAu;
  x0 += ks0; x1 += ks1;
#define TF_R(r) { x0 += x1; x1 = rotl32(x1, (r)); x1 ^= x0; }
  TF_R(13) TF_R(15) TF_R(26) TF_R(6)
  x0 += ks1; x1 += ks2 + 1u;
  TF_R(17) TF_R(29) TF_R(16) TF_R(24)
  x0 += ks2; x1 += ks0 + 2u;
  TF_R(13) TF_R(15) TF_R(26) TF_R(6)
  x0 += ks0; x1 += ks1 + 3u;
  TF_R(17) TF_R(29) TF_R(16) TF_R(24)
  x0 += ks1; x1 += ks2 + 4u;
  TF_R(13) TF_R(15) TF_R(26) TF_R(6)
  x0 += ks2; x1 += ks0 + 5u;
#undef TF_R
}

// bits -> uniform(-1+2^-24, 1) -> laplace -> /5  (exact JAX op sequence)
__device__ __forceinline__ float bits_to_noise(unsigned bits) {
  unsigned fb = (bits >> 9) | 0x3F800000u;
  float f = __uint_as_float(fb) - 1.0f;
  const float minv = -0.99999994039535522461f;
  float u = __fadd_rn(__fmul_rn(f, 2.0f), minv);
  u = fmaxf(minv, u);
  float s = (u > 0.0f) ? 1.0f : ((u < 0.0f) ? -1.0f : 0.0f);
  float l = s * log1pf(-fabsf(u));
  return __fdiv_rn(l, 5.0f);
}

__device__ __forceinline__ float bf2f(unsigned short b) {
  return __uint_as_float(((unsigned)b) << 16);
}
__device__ __forceinline__ unsigned short f2bf(float x) {
  __hip_bfloat16 h = __float2bfloat16(x);   // RNE
  return *(unsigned short*)&h;
}

// order-preserving (value, index) packing: bigger u64 = larger val, ties->lower idx
__device__ __forceinline__ u64 pack_maxidx(float v, unsigned idx) {
  unsigned b = __float_as_uint(v);
  unsigned key = (b & 0x80000000u) ? ~b : (b | 0x80000000u);
  return ((u64)key << 32) | (u64)(0xFFFFFFFFu - idx);
}
__device__ __forceinline__ u64 umax64(u64 a, u64 b) { return a > b ? a : b; }

// swizzle: byte ^= ((byte>>7)&3)<<4  (involution; rows land on distinct banks)
__device__ __forceinline__ int swz(int byte) {
  return byte ^ (((byte >> 7) & 3) << 4);
}

__device__ __forceinline__ void gload16(const void* g, void* l) {
  __builtin_amdgcn_global_load_lds(
      (const __attribute__((address_space(1))) unsigned*)g,
      (__attribute__((address_space(3))) unsigned*)l, 16, 0, 0);
}

// ============================ FAST PATH ====================================

// noisy(f32)->d_out, plus split bf16 hi/lo to ws
__global__ void noise_split_kernel(const float* __restrict__ in,
                                   float* __restrict__ noisy,
                                   unsigned short* __restrict__ Ah,
                                   unsigned short* __restrict__ Al) {
  const unsigned i = blockIdx.x * blockDim.x + threadIdx.x;
  if (i >= EMB_N) return;
  unsigned x0 = 0u, x1 = i;
  threefry2x32_042(x0, x1);
  float v = in[i] + bits_to_noise(x0 ^ x1);
  noisy[i] = v;
  unsigned short hb = f2bf(v);
  Ah[i] = hb;
  Al[i] = f2bf(v - bf2f(hb));
}

// table split to bf16 hi/lo, padded rows zeroed
__global__ void bsplit_kernel(const float* __restrict__ tab,
                              unsigned short* __restrict__ Bh,
                              unsigned short* __restrict__ Bl) {
  const size_t i = ((size_t)blockIdx.x * blockDim.x + threadIdx.x) * 4;
  if (i >= (size_t)PADV * K_DIM) return;
  ushort4 h, l;
  if (i < (size_t)TAB_N) {
    float4 v = *(const float4*)(tab + i);
    h.x = f2bf(v.x); l.x = f2bf(v.x - bf2f(h.x));
    h.y = f2bf(v.y); l.y = f2bf(v.y - bf2f(h.y));
    h.z = f2bf(v.z); l.z = f2bf(v.z - bf2f(h.z));
    h.w = f2bf(v.w); l.w = f2bf(v.w - bf2f(h.w));
  } else {
    h = make_ushort4(0, 0, 0, 0); l = h;
  }
  *(ushort4*)(Bh + i) = h;
  *(ushort4*)(Bl + i) = l;
}

// bf16x3 MFMA GEMM; per row per split capture top-2 approx candidates
__global__ __launch_bounds__(256) void mfma_cand_kernel(
    const unsigned short* __restrict__ Ah, const unsigned short* __restrict__ Al,
    const unsigned short* __restrict__ Bh, const unsigned short* __restrict__ Bl,
    unsigned* __restrict__ cand) {
  __shared__ alignas(16) char lds[32768];           // Ah|Al|Bh|Bl tiles, 8KB each
  __shared__ u64 topscr[128][2][2];

  const int tid = threadIdx.x, lane = tid & 63, w = tid >> 6;
  const int fr = lane & 15, g = lane >> 4;
  const int wr = (w >> 1) * 64, wc = (w & 1) * 64;
  const int bm = blockIdx.x, split = blockIdx.y;

  // staging slots for this wave: s = w*128 + i*64 + lane
  int srow[2], skoff[2];
  char* sdst[2];
#pragma unroll
  for (int i = 0; i < 2; ++i) {
    int s = w * 128 + i * 64 + lane;
    int row = s >> 2, gl = s & 3;
    int gd = gl ^ ((row >> 1) & 3);
    srow[i] = row;
    skoff[i] = gd * 8;
    sdst[i] = lds + (w * 2048 + i * 1024);   // + lane*16 by HW
  }

  u64 run1 = 0, run2 = 0;   // running top-2 for row `tid` (tid<128)

  for (int t = split; t < NT128; t += GSPLIT) {
    f32x4 acc[4][4];
#pragma unroll
    for (int m = 0; m < 4; ++m)
#pragma unroll
      for (int n = 0; n < 4; ++n) acc[m][n] = (f32x4){0.f, 0.f, 0.f, 0.f};

    const size_t abase = (size_t)bm * 128 * K_DIM;
    const size_t bbase = (size_t)t * 128 * K_DIM;

    for (int ks = 0; ks < K_DIM / 32; ++ks) {
      __syncthreads();
#pragma unroll
      for (int i = 0; i < 2; ++i) {
        const size_t ka = abase + (size_t)srow[i] * K_DIM + ks * 32 + skoff[i];
        const size_t kb = bbase + (size_t)srow[i] * K_DIM + ks * 32 + skoff[i];
        gload16(Ah + ka, sdst[i]);
        gload16(Al + ka, sdst[i] + 8192);
        gload16(Bh + kb, sdst[i] + 16384);
        gload16(Bl + kb, sdst[i] + 24576);
      }
      __syncthreads();

      short8 ahf[4], alf[4], bhf[4], blf[4];
#pragma unroll
      for (int m = 0; m < 4; ++m) {
        int row = wr + m * 16 + fr;
        int byte = swz(row * 64 + g * 16);
        ahf[m] = *(const short8*)(lds + byte);
        alf[m] = *(const short8*)(lds + 8192 + byte);
      }
#pragma unroll
      for (int n = 0; n < 4; ++n) {
        int row = wc + n * 16 + fr;
        int byte = swz(row * 64 + g * 16);
        bhf[n] = *(const short8*)(lds + 16384 + byte);
        blf[n] = *(const short8*)(lds + 24576 + byte);
      }
#pragma unroll
      for (int m = 0; m < 4; ++m)
#pragma unroll
        for (int n = 0; n < 4; ++n) {
          acc[m][n] = __builtin_amdgcn_mfma_f32_16x16x32_bf16(ahf[m], bhf[n], acc[m][n], 0, 0, 0);
          acc[m][n] = __builtin_amdgcn_mfma_f32_16x16x32_bf16(ahf[m], blf[n], acc[m][n], 0, 0, 0);
          acc[m][n] = __builtin_amdgcn_mfma_f32_16x16x32_bf16(alf[m], bhf[n], acc[m][n], 0, 0, 0);
        }
    }

    // per-tile top-2 per row
    const int colb = t * 128 + wc + fr;
#pragma unroll
    for (int m = 0; m < 4; ++m)
#pragma unroll
      for (int j = 0; j < 4; ++j) {
        u64 t1 = 0, t2 = 0;
#pragma unroll
        for (int n = 0; n < 4; ++n) {
          int c = colb + n * 16;
          u64 p = pack_maxidx(acc[m][n][j], (c < V_DIM) ? (unsigned)c : 0u);
          if (p > t1) { t2 = t1; t1 = p; } else t2 = umax64(t2, p);
        }
#pragma unroll
        for (int msk = 1; msk < 16; msk <<= 1) {
          u64 o1 = (u64)__shfl_xor((long long)t1, msk, 64);
          u64 o2 = (u64)__shfl_xor((long long)t2, msk, 64);
          if (o1 > t1) { t2 = umax64(t1, o2); t1 = o1; }
          else t2 = umax64(t2, o1);
        }
        if (fr == 0) {
          int rl = wr + m * 16 + g * 4 + j;
          topscr[rl][w & 1][0] = t1;
          topscr[rl][w & 1][1] = t2;
        }
      }
    __syncthreads();
    if (tid < 128) {
      u64 a1 = topscr[tid][0][0], a2 = topscr[tid][0][1];
      u64 b1 = topscr[tid][1][0], b2 = topscr[tid][1][1];
      u64 m1, m2;
      if (a1 > b1) { m1 = a1; m2 = umax64(a2, b1); }
      else         { m1 = b1; m2 = umax64(b2, a1); }
      if (m1 > run1) { run2 = umax64(run1, m2); run1 = m1; }
      else run2 = umax64(run2, m1);
    }
  }

  if (tid < 128) {
    int grow = bm * 128 + tid;
    unsigned i1 = 0xFFFFFFFFu - (unsigned)(run1 & 0xFFFFFFFFull);
    unsigned i2 = 0xFFFFFFFFu - (unsigned)(run2 & 0xFFFFFFFFull);
    if (i1 >= V_DIM) i1 = 0;
    if (i2 >= V_DIM) i2 = 0;
    cand[(grow * GSPLIT + split) * 2 + 0] = i1;
    cand[(grow * GSPLIT + split) * 2 + 1] = i2;
  }
}

// exact fp32 rescore of 64 candidates/row, same fmaf order as verified kernel
__global__ void rescore_kernel(const float* __restrict__ noisy,
                               const float* __restrict__ table,
                               const unsigned* __restrict__ cand,
                               u64* __restrict__ merged) {
  const int row = blockIdx.x;
  const int lane = threadIdx.x;   // 64
  const unsigned ci = cand[row * NCAND + lane];
  const float* a = noisy + (size_t)row * K_DIM;
  const float* b = table + (size_t)ci * K_DIM;
  float s = 0.f;
  for (int k = 0; k < K_DIM; ++k) s = fmaf(a[k], b[k], s);
  u64 p = pack_maxidx(s, ci);
#pragma unroll
  for (int m = 1; m < 64; m <<= 1) {
    u64 o = (u64)__shfl_xor((long long)p, m, 64);
    if (o > p) p = o;
  }
  if (lane == 0) merged[row] = p;
}

// ============================ FALLBACK (verified round-6) ===================

__global__ void noise_add_kernel(const float* __restrict__ in,
                                 float* __restrict__ noisy,
                                 u64* __restrict__ merged) {
  const unsigned i = blockIdx.x * blockDim.x + threadIdx.x;
  if (i >= EMB_N) return;
  if (i < M_TOT) merged[i] = 0ull;
  unsigned x0 = 0u, x1 = i;
  threefry2x32_042(x0, x1);
  noisy[i] = in[i] + bits_to_noise(x0 ^ x1);
}

__global__ __launch_bounds__(256) void gemm_argmax_kernel(
    const float* __restrict__ noisy, const float* __restrict__ table,
    u64* __restrict__ merged) {
  __shared__ float As[16][132];
  __shared__ float Bs[16][132];
  __shared__ float redm[128][16];
  __shared__ int   redi[128][16];

  const int tid = threadIdx.x;
  const int lane = tid & 63;
  const int w = tid >> 6;
  const int tx = lane & 7, ty = lane >> 3;
  const int col0 = (w & 1) * 64 + tx * 8;
  const int row0 = (w >> 1) * 64 + ty * 8;
  const int bm = blockIdx.x;
  const int split = blockIdx.y;
  const float* Abase = noisy + (size_t)bm * 128 * K_DIM;

  float rmax[8]; int ridx[8];
#pragma unroll
  for (int r = 0; r < 8; ++r) { rmax[r] = -INFINITY; ridx[r] = 0x7FFFFFFF; }

  for (int t = split; t < NTILES; t += NSPLIT) {
    const int nbase = t * 128;
    float acc[8][8];
#pragma unroll
    for (int r = 0; r < 8; ++r)
#pragma unroll
      for (int c = 0; c < 8; ++c) acc[r][c] = 0.0f;

    for (int k0 = 0; k0 < K_DIM; k0 += 16) {
      __syncthreads();
#pragma unroll
      for (int l = 0; l < 2; ++l) {
        const int e = tid + l * 256;
        const int ml = e >> 2, kk = (e & 3) << 2;
        float4 av = *(const float4*)(Abase + (size_t)ml * K_DIM + k0 + kk);
        As[kk + 0][ml] = av.x; As[kk + 1][ml] = av.y;
        As[kk + 2][ml] = av.z; As[kk + 3][ml] = av.w;
        const int n = nbase + ml;
        float4 bv = make_float4(0.f, 0.f, 0.f, 0.f);
        if (n < V_DIM)
          bv = *(const float4*)(table + (size_t)n * K_DIM + k0 + kk);
        Bs[kk + 0][ml] = bv.x; Bs[kk + 1][ml] = bv.y;
        Bs[kk + 2][ml] = bv.z; Bs[kk + 3][ml] = bv.w;
      }
      __syncthreads();
#pragma unroll
      for (int k = 0; k < 16; ++k) {
        float4 a0 = *(const float4*)&As[k][row0];
        float4 a1 = *(const float4*)&As[k][row0 + 4];
        float4 b0 = *(const float4*)&Bs[k][col0];
        float4 b1 = *(const float4*)&Bs[k][col0 + 4];
        float a[8] = {a0.x, a0.y, a0.z, a0.w, a1.x, a1.y, a1.z, a1.w};
        float b[8] = {b0.x, b0.y, b0.z, b0.w, b1.x, b1.y, b1.z, b1.w};
#pragma unroll
        for (int r = 0; r < 8; ++r)
#pragma unroll
          for (int c = 0; c < 8; ++c)
            acc[r][c] = fmaf(a[r], b[c], acc[r][c]);
      }
    }
#pragma unroll
    for (int r = 0; r < 8; ++r)
#pragma unroll
      for (int c = 0; c < 8; ++c) {
        const int n = nbase + col0 + c;
        if (n < V_DIM && acc[r][c] > rmax[r]) { rmax[r] = acc[r][c]; ridx[r] = n; }
      }
  }

  __syncthreads();
#pragma unroll
  for (int r = 0; r < 8; ++r) {
    redm[row0 + r][(w & 1) * 8 + tx] = rmax[r];
    redi[row0 + r][(w & 1) * 8 + tx] = ridx[r];
  }
  __syncthreads();
  if (tid < 128) {
    float best = -INFINITY; int bi = 0x7FFFFFFF;
#pragma unroll
    for (int j = 0; j < 16; ++j) {
      float v = redm[tid][j]; int id = redi[tid][j];
      if (v > best || (v == best && id < bi)) { best = v; bi = id; }
    }
    atomicMax(&merged[bm * 128 + tid], pack_maxidx(best, (unsigned)bi));
  }
}

// ---------------- shared: unpack index + gather table row -------------------
__global__ void gather_kernel(const u64* __restrict__ merged,
                              const float* __restrict__ table,
                              float* __restrict__ out) {
  const int row = blockIdx.x;
  const int tid = threadIdx.x;
  const unsigned bi = 0xFFFFFFFFu - (unsigned)(merged[row] & 0xFFFFFFFFull);
  if (tid < 192) {
    float4 val = *(const float4*)(table + (size_t)bi * K_DIM + tid * 4);
    *(float4*)(out + (size_t)row * K_DIM + tid * 4) = val;
  }
}

// ---------------- launch ----------------
extern "C" void kernel_launch(void* const* d_in, const int* in_sizes, int n_in,
                              void* d_out, int out_size, void* d_ws, size_t ws_size,
                              hipStream_t stream) {
  const float* inputs = (const float*)d_in[0];
  const float* table  = (const float*)d_in[1];
  if (n_in >= 2 && (in_sizes[0] == TAB_N || in_sizes[1] == EMB_N)) {
    table  = (const float*)d_in[0];
    inputs = (const float*)d_in[1];
  }
  float* out = (float*)d_out;
  float* noisy = out;   // overwritten by gather at the end

  // fast-path ws layout (bytes)
  const size_t oAh = 0;
  const size_t oAl = oAh + (size_t)EMB_N * 2;            //   6,291,456
  const size_t oBh = oAl + (size_t)EMB_N * 2;            //  12,582,912
  const size_t oBl = oBh + (size_t)PADV * K_DIM * 2;     //  89,849,856
  const size_t oCand = oBl + (size_t)PADV * K_DIM * 2;   // 167,116,800
  const size_t oMerged = oCand + (size_t)M_TOT * NCAND * 4;
  const size_t REQ = oMerged + (size_t)M_TOT * 8;        // ~168.2 MB

  if (ws_size >= REQ) {
    unsigned short* Ah = (unsigned short*)((char*)d_ws + oAh);
    unsigned short* Al = (unsigned short*)((char*)d_ws + oAl);
    unsigned short* Bh = (unsigned short*)((char*)d_ws + oBh);
    unsigned short* Bl = (unsigned short*)((char*)d_ws + oBl);
    unsigned* cand = (unsigned*)((char*)d_ws + oCand);
    u64* merged = (u64*)((char*)d_ws + oMerged);

    noise_split_kernel<<<EMB_N / 256, 256, 0, stream>>>(inputs, noisy, Ah, Al);
    bsplit_kernel<<<(PADV * K_DIM / 4) / 256, 256, 0, stream>>>(table, Bh, Bl);
    dim3 g2(M_TOT / 128, GSPLIT);
    mfma_cand_kernel<<<g2, 256, 0, stream>>>(Ah, Al, Bh, Bl, cand);
    rescore_kernel<<<M_TOT, 64, 0, stream>>>(noisy, table, cand, merged);
    gather_kernel<<<M_TOT, 256, 0, stream>>>(merged, table, out);
  } else {
    u64* merged = (u64*)d_ws;
    noise_add_kernel<<<EMB_N / 256, 256, 0, stream>>>(inputs, noisy, merged);
    dim3 g2(M_TOT / 128, NSPLIT);
    gemm_argmax_kernel<<<g2, 256, 0, stream>>>(noisy, table, merged);
    gather_kernel<<<M_TOT, 256, 0, stream>>>(merged, table, out);
  }
}

// Round 8
// 682.597 us; speedup vs baseline: 6.2394x; 1.7732x over previous
//
#include <hip/hip_runtime.h>
#include <hip/hip_bf16.h>
#include <float.h>
#include <math.h>

#define K_DIM 768
#define V_DIM 50257
#define PADV  50304              // 393*128 padded vocab
#define M_TOT 4096
#define EMB_N 3145728            // 2*2048*768
#define TAB_N 38597376           // 50257*768
#define NT128 393                // N tiles of 128
#define GSPLIT 32                // N splits for MFMA kernel
#define NCAND 64                 // GSPLIT * top2
#define NSPLIT 16                // fallback fp32 kernel splits
#define NTILES ((V_DIM + 127) / 128)

typedef __attribute__((ext_vector_type(8))) short short8;
typedef __attribute__((ext_vector_type(4))) float f32x4;
typedef unsigned long long u64;

// ---------------- JAX threefry2x32 (key = (0, 42)), 20 rounds ----------------
__device__ __forceinline__ unsigned rotl32(unsigned v, int d) {
  return (v << d) | (v >> (32 - d));
}
__device__ __forceinline__ void threefry2x32_042(unsigned& x0, unsigned& x1) {
  const unsigned ks0 = 0u, ks1 = 42u;
  const unsigned ks2 = ks0 ^ ks1 ^ 0x1BD11BDAu;
  x0 += ks0; x1 += ks1;
#define TF_R(r) { x0 += x1; x1 = rotl32(x1, (r)); x1 ^= x0; }
  TF_R(13) TF_R(15) TF_R(26) TF_R(6)
  x0 += ks1; x1 += ks2 + 1u;
  TF_R(17) TF_R(29) TF_R(16) TF_R(24)
  x0 += ks2; x1 += ks0 + 2u;
  TF_R(13) TF_R(15) TF_R(26) TF_R(6)
  x0 += ks0; x1 += ks1 + 3u;
  TF_R(17) TF_R(29) TF_R(16) TF_R(24)
  x0 += ks1; x1 += ks2 + 4u;
  TF_R(13) TF_R(15) TF_R(26) TF_R(6)
  x0 += ks2; x1 += ks0 + 5u;
#undef TF_R
}

// bits -> uniform(-1+2^-24, 1) -> laplace -> /5  (exact JAX op sequence)
__device__ __forceinline__ float bits_to_noise(unsigned bits) {
  unsigned fb = (bits >> 9) | 0x3F800000u;
  float f = __uint_as_float(fb) - 1.0f;
  const float minv = -0.99999994039535522461f;
  float u = __fadd_rn(__fmul_rn(f, 2.0f), minv);
  u = fmaxf(minv, u);
  float s = (u > 0.0f) ? 1.0f : ((u < 0.0f) ? -1.0f : 0.0f);
  float l = s * log1pf(-fabsf(u));
  return __fdiv_rn(l, 5.0f);
}

__device__ __forceinline__ float bf2f(unsigned short b) {
  return __uint_as_float(((unsigned)b) << 16);
}
__device__ __forceinline__ unsigned short f2bf(float x) {
  __hip_bfloat16 h = __float2bfloat16(x);   // RNE
  return *(unsigned short*)&h;
}

// order-preserving (value, index) packing: bigger u64 = larger val, ties->lower idx
__device__ __forceinline__ u64 pack_maxidx(float v, unsigned idx) {
  unsigned b = __float_as_uint(v);
  unsigned key = (b & 0x80000000u) ? ~b : (b | 0x80000000u);
  return ((u64)key << 32) | (u64)(0xFFFFFFFFu - idx);
}
__device__ __forceinline__ u64 umax64(u64 a, u64 b) { return a > b ? a : b; }

__device__ __forceinline__ void gload16(const void* g, void* l) {
  __builtin_amdgcn_global_load_lds(
      (const __attribute__((address_space(1))) unsigned*)g,
      (__attribute__((address_space(3))) unsigned*)l, 16, 0, 0);
}

// ============================ FAST PATH ====================================

// noisy(f32)->d_out, plus bf16 hi to ws (hh-only GEMM; rescore is exact fp32)
__global__ void noise_split_kernel(const float* __restrict__ in,
                                   float* __restrict__ noisy,
                                   unsigned short* __restrict__ Ah) {
  const unsigned i = blockIdx.x * blockDim.x + threadIdx.x;
  if (i >= EMB_N) return;
  unsigned x0 = 0u, x1 = i;
  threefry2x32_042(x0, x1);
  float v = in[i] + bits_to_noise(x0 ^ x1);
  noisy[i] = v;
  Ah[i] = f2bf(v);
}

// table -> bf16, padded rows zeroed
__global__ void bsplit_kernel(const float* __restrict__ tab,
                              unsigned short* __restrict__ Bh) {
  const size_t i = ((size_t)blockIdx.x * blockDim.x + threadIdx.x) * 4;
  if (i >= (size_t)PADV * K_DIM) return;
  ushort4 h;
  if (i < (size_t)TAB_N) {
    float4 v = *(const float4*)(tab + i);
    h.x = f2bf(v.x); h.y = f2bf(v.y); h.z = f2bf(v.z); h.w = f2bf(v.w);
  } else {
    h = make_ushort4(0, 0, 0, 0);
  }
  *(ushort4*)(Bh + i) = h;
}

// bf16 MFMA GEMM (BK=64); per row per split capture top-2 approx candidates.
// LDS tile layout: 128 rows x 128B (64 bf16); 16B-slot p within a row is
// XOR-swizzled: stored chunk q at slot p = q ^ (row&7). Staged via linear
// global_load_lds with pre-swizzled global source (rule: both sides, same
// involution). Reads: 16 lanes hit 8 distinct slots -> 2-way = free.
__global__ __launch_bounds__(256) void mfma_cand_kernel(
    const unsigned short* __restrict__ Ah,
    const unsigned short* __restrict__ Bh,
    unsigned* __restrict__ cand) {
  __shared__ alignas(16) char ldsA[16384];
  __shared__ alignas(16) char ldsB[16384];
  __shared__ u64 topscr[128][2][2];

  const int tid = threadIdx.x, lane = tid & 63, w = tid >> 6;
  const int fr = lane & 15, g = lane >> 4;
  const int wr = (w >> 1) * 64, wc = (w & 1) * 64;
  const int bm = blockIdx.x, split = blockIdx.y;

  // staging descriptors: 4 issues per operand per K-step (16KB / 256 / 16B)
  int srow[4], scol[4], soff[4];
#pragma unroll
  for (int i = 0; i < 4; ++i) {
    int s = i * 256 + w * 64 + lane;        // LDS 16B-slot index 0..1023
    int row = s >> 3, p = s & 7;
    srow[i] = row;
    scol[i] = (p ^ (row & 7)) * 8;          // source element offset (bf16)
    soff[i] = i * 4096 + w * 1024;          // wave-uniform LDS byte base
  }

  u64 run1 = 0, run2 = 0;   // running top-2 for row `tid` (tid<128)

  for (int t = split; t < NT128; t += GSPLIT) {
    f32x4 acc[4][4];
#pragma unroll
    for (int m = 0; m < 4; ++m)
#pragma unroll
      for (int n = 0; n < 4; ++n) acc[m][n] = (f32x4){0.f, 0.f, 0.f, 0.f};

    const size_t abase = (size_t)bm * 128 * K_DIM;
    const size_t bbase = (size_t)t * 128 * K_DIM;

    for (int ks = 0; ks < K_DIM / 64; ++ks) {
      const int k0 = ks * 64;
      __syncthreads();
#pragma unroll
      for (int i = 0; i < 4; ++i) {
        gload16(Ah + abase + (size_t)srow[i] * K_DIM + k0 + scol[i], ldsA + soff[i]);
        gload16(Bh + bbase + (size_t)srow[i] * K_DIM + k0 + scol[i], ldsB + soff[i]);
      }
      __syncthreads();

      short8 af[4][2], bf[4][2];
#pragma unroll
      for (int m = 0; m < 4; ++m) {
        const int row = wr + m * 16 + fr;
#pragma unroll
        for (int k2 = 0; k2 < 2; ++k2) {
          const int p = (k2 * 4 + g) ^ (row & 7);
          af[m][k2] = *(const short8*)(ldsA + row * 128 + p * 16);
        }
      }
#pragma unroll
      for (int n = 0; n < 4; ++n) {
        const int row = wc + n * 16 + fr;
#pragma unroll
        for (int k2 = 0; k2 < 2; ++k2) {
          const int p = (k2 * 4 + g) ^ (row & 7);
          bf[n][k2] = *(const short8*)(ldsB + row * 128 + p * 16);
        }
      }
#pragma unroll
      for (int m = 0; m < 4; ++m)
#pragma unroll
        for (int n = 0; n < 4; ++n) {
          acc[m][n] = __builtin_amdgcn_mfma_f32_16x16x32_bf16(af[m][0], bf[n][0], acc[m][n], 0, 0, 0);
          acc[m][n] = __builtin_amdgcn_mfma_f32_16x16x32_bf16(af[m][1], bf[n][1], acc[m][n], 0, 0, 0);
        }
    }

    // per-tile top-2 per row (C/D: col=lane&15 -> vocab, row=g*4+j -> M)
    const int colb = t * 128 + wc + fr;
#pragma unroll
    for (int m = 0; m < 4; ++m)
#pragma unroll
      for (int j = 0; j < 4; ++j) {
        u64 t1 = 0, t2 = 0;
#pragma unroll
        for (int n = 0; n < 4; ++n) {
          int c = colb + n * 16;
          u64 p = pack_maxidx(acc[m][n][j], (c < V_DIM) ? (unsigned)c : 0u);
          if (p > t1) { t2 = t1; t1 = p; } else t2 = umax64(t2, p);
        }
#pragma unroll
        for (int msk = 1; msk < 16; msk <<= 1) {
          u64 o1 = (u64)__shfl_xor((long long)t1, msk, 64);
          u64 o2 = (u64)__shfl_xor((long long)t2, msk, 64);
          if (o1 > t1) { t2 = umax64(t1, o2); t1 = o1; }
          else t2 = umax64(t2, o1);
        }
        if (fr == 0) {
          int rl = wr + m * 16 + g * 4 + j;
          topscr[rl][w & 1][0] = t1;
          topscr[rl][w & 1][1] = t2;
        }
      }
    __syncthreads();
    if (tid < 128) {
      u64 a1 = topscr[tid][0][0], a2 = topscr[tid][0][1];
      u64 b1 = topscr[tid][1][0], b2 = topscr[tid][1][1];
      u64 m1, m2;
      if (a1 > b1) { m1 = a1; m2 = umax64(a2, b1); }
      else         { m1 = b1; m2 = umax64(b2, a1); }
      if (m1 > run1) { run2 = umax64(run1, m2); run1 = m1; }
      else run2 = umax64(run2, m1);
    }
  }

  if (tid < 128) {
    int grow = bm * 128 + tid;
    unsigned i1 = 0xFFFFFFFFu - (unsigned)(run1 & 0xFFFFFFFFull);
    unsigned i2 = 0xFFFFFFFFu - (unsigned)(run2 & 0xFFFFFFFFull);
    if (i1 >= V_DIM) i1 = 0;
    if (i2 >= V_DIM) i2 = 0;
    cand[(grow * GSPLIT + split) * 2 + 0] = i1;
    cand[(grow * GSPLIT + split) * 2 + 1] = i2;
  }
}

// exact fp32 rescore of 64 candidates/row (sequential fmaf, verified order)
__global__ void rescore_kernel(const float* __restrict__ noisy,
                               const float* __restrict__ table,
                               const unsigned* __restrict__ cand,
                               u64* __restrict__ merged) {
  const int row = blockIdx.x;
  const int lane = threadIdx.x;   // 64
  const unsigned ci = cand[row * NCAND + lane];
  const float* a = noisy + (size_t)row * K_DIM;
  const float* b = table + (size_t)ci * K_DIM;
  float s = 0.f;
  for (int k = 0; k < K_DIM; ++k) s = fmaf(a[k], b[k], s);
  u64 p = pack_maxidx(s, ci);
#pragma unroll
  for (int m = 1; m < 64; m <<= 1) {
    u64 o = (u64)__shfl_xor((long long)p, m, 64);
    if (o > p) p = o;
  }
  if (lane == 0) merged[row] = p;
}

// ============================ FALLBACK (verified round-6) ===================

__global__ void noise_add_kernel(const float* __restrict__ in,
                                 float* __restrict__ noisy,
                                 u64* __restrict__ merged) {
  const unsigned i = blockIdx.x * blockDim.x + threadIdx.x;
  if (i >= EMB_N) return;
  if (i < M_TOT) merged[i] = 0ull;
  unsigned x0 = 0u, x1 = i;
  threefry2x32_042(x0, x1);
  noisy[i] = in[i] + bits_to_noise(x0 ^ x1);
}

__global__ __launch_bounds__(256) void gemm_argmax_kernel(
    const float* __restrict__ noisy, const float* __restrict__ table,
    u64* __restrict__ merged) {
  __shared__ float As[16][132];
  __shared__ float Bs[16][132];
  __shared__ float redm[128][16];
  __shared__ int   redi[128][16];

  const int tid = threadIdx.x;
  const int lane = tid & 63;
  const int w = tid >> 6;
  const int tx = lane & 7, ty = lane >> 3;
  const int col0 = (w & 1) * 64 + tx * 8;
  const int row0 = (w >> 1) * 64 + ty * 8;
  const int bm = blockIdx.x;
  const int split = blockIdx.y;
  const float* Abase = noisy + (size_t)bm * 128 * K_DIM;

  float rmax[8]; int ridx[8];
#pragma unroll
  for (int r = 0; r < 8; ++r) { rmax[r] = -INFINITY; ridx[r] = 0x7FFFFFFF; }

  for (int t = split; t < NTILES; t += NSPLIT) {
    const int nbase = t * 128;
    float acc[8][8];
#pragma unroll
    for (int r = 0; r < 8; ++r)
#pragma unroll
      for (int c = 0; c < 8; ++c) acc[r][c] = 0.0f;

    for (int k0 = 0; k0 < K_DIM; k0 += 16) {
      __syncthreads();
#pragma unroll
      for (int l = 0; l < 2; ++l) {
        const int e = tid + l * 256;
        const int ml = e >> 2, kk = (e & 3) << 2;
        float4 av = *(const float4*)(Abase + (size_t)ml * K_DIM + k0 + kk);
        As[kk + 0][ml] = av.x; As[kk + 1][ml] = av.y;
        As[kk + 2][ml] = av.z; As[kk + 3][ml] = av.w;
        const int n = nbase + ml;
        float4 bv = make_float4(0.f, 0.f, 0.f, 0.f);
        if (n < V_DIM)
          bv = *(const float4*)(table + (size_t)n * K_DIM + k0 + kk);
        Bs[kk + 0][ml] = bv.x; Bs[kk + 1][ml] = bv.y;
        Bs[kk + 2][ml] = bv.z; Bs[kk + 3][ml] = bv.w;
      }
      __syncthreads();
#pragma unroll
      for (int k = 0; k < 16; ++k) {
        float4 a0 = *(const float4*)&As[k][row0];
        float4 a1 = *(const float4*)&As[k][row0 + 4];
        float4 b0 = *(const float4*)&Bs[k][col0];
        float4 b1 = *(const float4*)&Bs[k][col0 + 4];
        float a[8] = {a0.x, a0.y, a0.z, a0.w, a1.x, a1.y, a1.z, a1.w};
        float b[8] = {b0.x, b0.y, b0.z, b0.w, b1.x, b1.y, b1.z, b1.w};
#pragma unroll
        for (int r = 0; r < 8; ++r)
#pragma unroll
          for (int c = 0; c < 8; ++c)
            acc[r][c] = fmaf(a[r], b[c], acc[r][c]);
      }
    }
#pragma unroll
    for (int r = 0; r < 8; ++r)
#pragma unroll
      for (int c = 0; c < 8; ++c) {
        const int n = nbase + col0 + c;
        if (n < V_DIM && acc[r][c] > rmax[r]) { rmax[r] = acc[r][c]; ridx[r] = n; }
      }
  }

  __syncthreads();
#pragma unroll
  for (int r = 0; r < 8; ++r) {
    redm[row0 + r][(w & 1) * 8 + tx] = rmax[r];
    redi[row0 + r][(w & 1) * 8 + tx] = ridx[r];
  }
  __syncthreads();
  if (tid < 128) {
    float best = -INFINITY; int bi = 0x7FFFFFFF;
#pragma unroll
    for (int j = 0; j < 16; ++j) {
      float v = redm[tid][j]; int id = redi[tid][j];
      if (v > best || (v == best && id < bi)) { best = v; bi = id; }
    }
    atomicMax(&merged[bm * 128 + tid], pack_maxidx(best, (unsigned)bi));
  }
}

// ---------------- shared: unpack index + gather table row -------------------
__global__ void gather_kernel(const u64* __restrict__ merged,
                              const float* __restrict__ table,
                              float* __restrict__ out) {
  const int row = blockIdx.x;
  const int tid = threadIdx.x;
  const unsigned bi = 0xFFFFFFFFu - (unsigned)(merged[row] & 0xFFFFFFFFull);
  if (tid < 192) {
    float4 val = *(const float4*)(table + (size_t)bi * K_DIM + tid * 4);
    *(float4*)(out + (size_t)row * K_DIM + tid * 4) = val;
  }
}

// ---------------- launch ----------------
extern "C" void kernel_launch(void* const* d_in, const int* in_sizes, int n_in,
                              void* d_out, int out_size, void* d_ws, size_t ws_size,
                              hipStream_t stream) {
  const float* inputs = (const float*)d_in[0];
  const float* table  = (const float*)d_in[1];
  if (n_in >= 2 && (in_sizes[0] == TAB_N || in_sizes[1] == EMB_N)) {
    table  = (const float*)d_in[0];
    inputs = (const float*)d_in[1];
  }
  float* out = (float*)d_out;
  float* noisy = out;   // overwritten by gather at the end

  // fast-path ws layout (bytes)
  const size_t oAh = 0;
  const size_t oBh = oAh + (size_t)EMB_N * 2;            //  6,291,456
  const size_t oCand = oBh + (size_t)PADV * K_DIM * 2;   // 83,558,400
  const size_t oMerged = oCand + (size_t)M_TOT * NCAND * 4;
  const size_t REQ = oMerged + (size_t)M_TOT * 8;        // ~84.6 MB

  if (ws_size >= REQ) {
    unsigned short* Ah = (unsigned short*)((char*)d_ws + oAh);
    unsigned short* Bh = (unsigned short*)((char*)d_ws + oBh);
    unsigned* cand = (unsigned*)((char*)d_ws + oCand);
    u64* merged = (u64*)((char*)d_ws + oMerged);

    noise_split_kernel<<<EMB_N / 256, 256, 0, stream>>>(inputs, noisy, Ah);
    bsplit_kernel<<<(PADV * K_DIM / 4) / 256, 256, 0, stream>>>(table, Bh);
    dim3 g2(M_TOT / 128, GSPLIT);
    mfma_cand_kernel<<<g2, 256, 0, stream>>>(Ah, Bh, cand);
    rescore_kernel<<<M_TOT, 64, 0, stream>>>(noisy, table, cand, merged);
    gather_kernel<<<M_TOT, 256, 0, stream>>>(merged, table, out);
  } else {
    u64* merged = (u64*)d_ws;
    noise_add_kernel<<<EMB_N / 256, 256, 0, stream>>>(inputs, noisy, merged);
    dim3 g2(M_TOT / 128, NSPLIT);
    gemm_argmax_kernel<<<g2, 256, 0, stream>>>(noisy, table, merged);
    gather_kernel<<<M_TOT, 256, 0, stream>>>(merged, table, out);
  }
}